// Round 11
// baseline (194.114 us; speedup 1.0000x reference)
//
#include <hip/hip_runtime.h>
#include <math.h>

constexpr int NU = 100000;
constexpr int NI = 50000;
constexpr int NN = 150000;   // NU + NI
constexpr int D  = 64;
constexpr int NE = 1200000;
constexpr int NE4 = NE / 4;
constexpr int B  = 4096;
constexpr int CAPB = 64;     // max in-degree of a batch col   (Poisson(8): max ~35)
constexpr int CAP2 = 40;     // max in-degree of a marked col  (P(>=40) ~ 1e-10)

// LDS degree histogram geometry
constexpr int NCHUNK = 3;
constexpr int CHUNK  = 65536;        // nodes per chunk (byte counters -> 64 KB LDS)
constexpr int CWORDS = CHUNK / 4;    // 16384 words
constexpr int WORDS  = 37504;        // padded word stride per slice copy (NN/4 = 37500)
constexpr int RWORDS = 37500;        // real words
constexpr int NSLICE = 80;
constexpr int SLICE4 = NE4 / NSLICE; // 3750 int4 per slice

// flags bits: bit0 = batch col (score2 target), bit1 = needed row for gather1/MLP1

// ---- claim batch nodes; dense-remap them to bidx in [0, nb) ----
__global__ void k_flag(const int* __restrict__ users, const int* __restrict__ items,
                       int* flags, int* __restrict__ bidx, int* __restrict__ nb) {
    const int t = blockIdx.x * blockDim.x + threadIdx.x;
    if (t >= 2 * B) return;
    const int node = (t < B) ? users[t] : items[t - B] + NU;
    const int old = atomicOr(&flags[node], 1);
    if (!(old & 1)) bidx[node] = atomicAdd(nb, 1);   // unique claimer assigns index
}

// ---- degree histogram, zero global atomics: per-(chunk,slice) byte-packed LDS
//      histogram, flushed to a private copy. Safe: max degree ~35 << 255. ----
__global__ void __launch_bounds__(256) k_hist(const int* __restrict__ row,
                                              unsigned int* __restrict__ hcopy) {
    __shared__ unsigned int lh[CWORDS];
    const int ci = blockIdx.x / NSLICE;
    const int si = blockIdx.x % NSLICE;
    const int lo = ci * CHUNK;
    const int cw = (ci == NCHUNK - 1) ? (WORDS - (NCHUNK - 1) * CWORDS) : CWORDS;
    for (int w = threadIdx.x; w < cw; w += 256) lh[w] = 0;
    __syncthreads();
    const int4* r4 = reinterpret_cast<const int4*>(row) + (size_t)si * SLICE4;
    const unsigned int span = (unsigned)(cw * 4);
    for (int t = threadIdx.x; t < SLICE4; t += 256) {
        const int4 r = r4[t];
        int v;
        v = r.x - lo; if ((unsigned)v < span) atomicAdd(&lh[v >> 2], 1u << (8 * (v & 3)));
        v = r.y - lo; if ((unsigned)v < span) atomicAdd(&lh[v >> 2], 1u << (8 * (v & 3)));
        v = r.z - lo; if ((unsigned)v < span) atomicAdd(&lh[v >> 2], 1u << (8 * (v & 3)));
        v = r.w - lo; if ((unsigned)v < span) atomicAdd(&lh[v >> 2], 1u << (8 * (v & 3)));
    }
    __syncthreads();
    unsigned int* dst = hcopy + (size_t)si * WORDS + ci * CWORDS;
    for (int w = threadIdx.x; w < cw; w += 256) dst[w] = lh[w];
}

// ---- full edge pass: batch-col fixed-slot CSR fill + mark source rows (bit1) ----
__global__ void k_mark(const int* __restrict__ row, const int* __restrict__ col,
                       const int* __restrict__ bidx,
                       int* __restrict__ cntBd, int* __restrict__ csrBd, int* flags) {
    const int t = blockIdx.x * blockDim.x + threadIdx.x;
    if (t >= NE4) return;
    const int4 r = reinterpret_cast<const int4*>(row)[t];
    const int4 c = reinterpret_cast<const int4*>(col)[t];
    // flags[rr] |= 2 races only with other |=2 (bit0 frozen since k_flag) -> benign
    #define E1(rr, cc) if (flags[cc] & 1) { \
        const int bi = bidx[cc]; \
        const int s = atomicAdd(&cntBd[bi], 1); \
        csrBd[bi * CAPB + s] = rr; \
        flags[rr] |= 2; }
    E1(r.x, c.x) E1(r.y, c.y) E1(r.z, c.z) E1(r.w, c.w)
    #undef E1
}

// ---- reduce 80 histogram copies -> deg -> dinv, fused with bit1-list compaction ----
__global__ void k_dinvc(const unsigned int* __restrict__ hcopy,
                        float* __restrict__ dinv, const int* __restrict__ flags,
                        int* __restrict__ list, int* __restrict__ ncnt) {
    const int w = blockIdx.x * blockDim.x + threadIdx.x;
    if (w >= RWORDS) return;
    unsigned int s = 0;
    #pragma unroll 8
    for (int si = 0; si < NSLICE; ++si) s += hcopy[(size_t)si * WORDS + w];
    const int d0 = s & 255, d1 = (s >> 8) & 255, d2 = (s >> 16) & 255, d3 = (int)(s >> 24);
    float4 dv;
    dv.x = d0 > 0 ? 1.0f / sqrtf((float)d0) : 0.0f;
    dv.y = d1 > 0 ? 1.0f / sqrtf((float)d1) : 0.0f;
    dv.z = d2 > 0 ? 1.0f / sqrtf((float)d2) : 0.0f;
    dv.w = d3 > 0 ? 1.0f / sqrtf((float)d3) : 0.0f;
    reinterpret_cast<float4*>(dinv)[w] = dv;
    const int4 fl = reinterpret_cast<const int4*>(flags)[w];
    const int n0 = w * 4;
    if (fl.x & 2) list[atomicAdd(ncnt, 1)] = n0;       // wave-aggregated by compiler
    if (fl.y & 2) list[atomicAdd(ncnt, 1)] = n0 + 1;
    if (fl.z & 2) list[atomicAdd(ncnt, 1)] = n0 + 2;
    if (fl.w & 2) list[atomicAdd(ncnt, 1)] = n0 + 3;
}

// ---- pass 2: fill fixed-slot gather CSR for marked cols (single pass, no scan) ----
__global__ void k_pass2(const int* __restrict__ row, const int* __restrict__ col,
                        const int* __restrict__ flags,
                        int* __restrict__ cnt2d, int* __restrict__ csr2d) {
    const int t = blockIdx.x * blockDim.x + threadIdx.x;
    if (t >= NE4) return;
    const int4 r = reinterpret_cast<const int4*>(row)[t];
    const int4 c = reinterpret_cast<const int4*>(col)[t];
    #define E2(rr, cc) if (flags[cc] & 2) { \
        const int s = atomicAdd(&cnt2d[cc], 1); \
        csr2d[cc * CAP2 + s] = rr; }
    E2(r.x, c.x) E2(r.y, c.y) E2(r.z, c.z) E2(r.w, c.w)
    #undef E2
}

// ---- fused propagate-1 + MLP1, lazily: grid-stride, one wave per listed node.
// Gather: 4-deep ILP via int4 edge reads. MLP: x held across lanes; y[lane] =
// relu(b1[lane] + sum_k readlane(x,k) * W1[lane][k]) with W1 transposed in LDS
// (conflict-free: lane j reads sWt[k*64+j]). Per-node MLP math identical in
// form/order to the previous standalone kernel. ----
__global__ void __launch_bounds__(256) k_gmlp(const int* __restrict__ list,
                                              const int* __restrict__ ncnt,
                                              const int* __restrict__ cnt2d,
                                              const int* __restrict__ csr2d,
                                              const float* __restrict__ dinv,
                                              const float* __restrict__ embU,
                                              const float* __restrict__ embI,
                                              const float* __restrict__ W,
                                              const float* __restrict__ b,
                                              float* __restrict__ emb) {
    __shared__ float sWt[D * D];   // sWt[k*D + j] = W[j*D + k]
    __shared__ float sb[D];
    for (int i = threadIdx.x; i < D * D; i += blockDim.x)
        sWt[i] = W[(size_t)(i & 63) * D + (i >> 6)];
    if (threadIdx.x < D) sb[threadIdx.x] = b[threadIdx.x];
    __syncthreads();

    const int lane = threadIdx.x & 63;
    const int n = *ncnt;
    const int nwv = gridDim.x * (blockDim.x >> 6);
    for (int idx = blockIdx.x * (blockDim.x >> 6) + (threadIdx.x >> 6);
         idx < n; idx += nwv) {
        const int c = list[idx];
        const int ne = cnt2d[c];
        const int* es = csr2d + (size_t)c * CAP2;
        float a0 = 0.0f, a1 = 0.0f, a2 = 0.0f, a3 = 0.0f;
        int e = 0;
        for (; e + 3 < ne; e += 4) {       // 4-deep ILP: one int4 + 8 loads in flight
            const int4 r = *reinterpret_cast<const int4*>(es + e);
            const float d0 = dinv[r.x], d1 = dinv[r.y], d2 = dinv[r.z], d3 = dinv[r.w];
            const float* s0 = (r.x < NU) ? embU + (size_t)r.x * D : embI + (size_t)(r.x - NU) * D;
            const float* s1 = (r.y < NU) ? embU + (size_t)r.y * D : embI + (size_t)(r.y - NU) * D;
            const float* s2 = (r.z < NU) ? embU + (size_t)r.z * D : embI + (size_t)(r.z - NU) * D;
            const float* s3 = (r.w < NU) ? embU + (size_t)r.w * D : embI + (size_t)(r.w - NU) * D;
            a0 = fmaf(d0, s0[lane], a0);
            a1 = fmaf(d1, s1[lane], a1);
            a2 = fmaf(d2, s2[lane], a2);
            a3 = fmaf(d3, s3[lane], a3);
        }
        for (; e < ne; ++e) {
            const int r = es[e];
            const float* s = (r < NU) ? embU + (size_t)r * D : embI + (size_t)(r - NU) * D;
            a0 = fmaf(dinv[r], s[lane], a0);
        }
        const float x = dinv[c] * ((a0 + a1) + (a2 + a3));   // prop-1 value at lane
        float y = sb[lane];
        #pragma unroll
        for (int k = 0; k < D; ++k)
            y = fmaf(__int_as_float(__builtin_amdgcn_readlane(__float_as_int(x), k)),
                     sWt[k * D + lane], y);
        emb[(size_t)c * D + lane] = fmaxf(y, 0.0f);
    }
}

// ---- fused propagate2(batch fixed-slot CSR) + MLP2 + dot, per batch pair ----
__global__ void k_score2(const int* __restrict__ users, const int* __restrict__ items,
                         const int* __restrict__ bidx, const int* __restrict__ cntBd,
                         const int* __restrict__ csrBd,
                         const float* __restrict__ dinv, const float* __restrict__ embA,
                         const float* __restrict__ W, const float* __restrict__ b,
                         float* __restrict__ out) {
    __shared__ float sWt[D * D];   // sWt[k*D + j] = W[j*D + k]
    __shared__ float sb[D];
    __shared__ float sx[4][D];
    for (int i = threadIdx.x; i < D * D; i += blockDim.x)
        sWt[i] = W[(size_t)(i & 63) * D + (i >> 6)];
    if (threadIdx.x < D) sb[threadIdx.x] = b[threadIdx.x];
    __syncthreads();
    const int lane = threadIdx.x & 63;
    const int wid  = threadIdx.x >> 6;
    const int p = blockIdx.x * (blockDim.x >> 6) + wid;
    if (p >= B) return;

    float y[2];
    const int node[2] = { users[p], items[p] + NU };
    #pragma unroll
    for (int t = 0; t < 2; ++t) {
        const int c = node[t];
        const int bi = bidx[c];
        const int n = cntBd[bi];
        const int* es = csrBd + (size_t)bi * CAPB;
        float acc = 0.0f;
        for (int e = 0; e < n; ++e) {
            const int r = es[e];
            acc = fmaf(dinv[r], embA[(size_t)r * D + lane], acc);
        }
        sx[wid][lane] = dinv[c] * acc;
        float yv = sb[lane];
        #pragma unroll
        for (int k = 0; k < D; ++k)
            yv = fmaf(sx[wid][k], sWt[k * D + lane], yv);
        y[t] = yv;
    }
    float prod = y[0] * y[1];
    #pragma unroll
    for (int off = 32; off >= 1; off >>= 1) prod += __shfl_down(prod, off, 64);
    if (lane == 0) out[p] = prod;
}

extern "C" void kernel_launch(void* const* d_in, const int* in_sizes, int n_in,
                              void* d_out, int out_size, void* d_ws, size_t ws_size,
                              hipStream_t stream) {
    const int*   users    = (const int*)d_in[0];
    const int*   items    = (const int*)d_in[1];
    const int*   edge     = (const int*)d_in[2];   // [2][NE]
    const float* user_emb = (const float*)d_in[3];
    const float* item_emb = (const float*)d_in[4];
    const float* W1       = (const float*)d_in[5];
    const float* b1       = (const float*)d_in[6];
    const float* W2       = (const float*)d_in[7];
    const float* b2       = (const float*)d_in[8];
    float*       out      = (float*)d_out;

    const int* row  = edge;
    const int* colp = edge + NE;

    // workspace layout (int offsets; zeroed region contiguous at the front):
    int*   flags = (int*)d_ws;                  // @0        150016  [zeroed]
    int*   cnt2d = (int*)d_ws + 150016;         //           150016  [zeroed]
    int*   cntBd = (int*)d_ws + 300032;         //           8448    [zeroed]
    int*   nb    = (int*)d_ws + 308480;         //           16      [zeroed]
    int*   ncnt  = (int*)d_ws + 308496;         //           16     (zero ends 308512)
    float* dinv  = (float*)d_ws + 308512;       //           150016
    int*   bidx  = (int*)d_ws + 458528;         //           150016
    int*   list  = (int*)d_ws + 608544;         //           150016
    int*   csrBd = (int*)d_ws + 758560;         //           540672 (8448*64)
    int*   csr2d = (int*)d_ws + 1299232;        //           6000640 (150016*40)
    float* embA  = (float*)d_ws + 7299872;      //           9600000
    // hcopy (80*37504 = 3000320 ints) aliases csr2d: dead until k_pass2 runs,
    // and k_dinvc (its last reader) precedes k_pass2.
    unsigned int* hcopy = (unsigned int*)csr2d;

    hipMemsetAsync(flags, 0, (size_t)308512 * sizeof(int), stream);

    k_flag <<<(2 * B + 255) / 256, 256, 0, stream>>>(users, items, flags, bidx, nb);
    // degree histogram via LDS byte counters (no global atomics)
    k_hist <<<NCHUNK * NSLICE, 256, 0, stream>>>(row, hcopy);
    // batch CSR fill + source marking, one full edge pass
    k_mark <<<(NE4 + 255) / 256, 256, 0, stream>>>(row, colp, bidx, cntBd, csrBd, flags);
    // reduce histogram copies -> dinv ; compact bit1 list
    k_dinvc<<<(RWORDS + 255) / 256, 256, 0, stream>>>(hcopy, dinv, flags, list, ncnt);
    // gather CSR fill (marked cols only), one full edge pass, no scans
    k_pass2<<<(NE4 + 255) / 256, 256, 0, stream>>>(row, colp, flags, cnt2d, csr2d);

    // fused lazy propagate-1 + MLP1 (grid-stride; W1 staged once per block)
    k_gmlp <<<2560, 256, 0, stream>>>(list, ncnt, cnt2d, csr2d, dinv,
                                      user_emb, item_emb, W1, b1, embA);
    // fused propagate-2 + MLP2 + dot at the 4096 batch pairs
    k_score2<<<B / 4, 256, 0, stream>>>(users, items, bidx, cntBd, csrBd, dinv, embA,
                                        W2, b2, out);
}

// Round 12
// 178.173 us; speedup vs baseline: 1.0895x; 1.0895x over previous
//
#include <hip/hip_runtime.h>
#include <math.h>

constexpr int NU = 100000;
constexpr int NI = 50000;
constexpr int NN = 150000;   // NU + NI
constexpr int D  = 64;
constexpr int NE = 1200000;
constexpr int NE4 = NE / 4;
constexpr int B  = 4096;
constexpr int CAPB = 64;     // max in-degree of a batch col   (Poisson(8): max ~35)
constexpr int CAP2 = 40;     // max in-degree of a marked col  (P(>=40) ~ 1e-10)

// LDS degree histogram geometry
constexpr int NCHUNK = 3;
constexpr int CHUNK  = 65536;        // nodes per chunk (byte counters -> 64 KB LDS)
constexpr int CWORDS = CHUNK / 4;    // 16384 words
constexpr int WORDS  = 37504;        // padded word stride per slice copy (NN/4 = 37500)
constexpr int RWORDS = 37500;        // real words
constexpr int NSLICE = 80;
constexpr int SLICE4 = NE4 / NSLICE; // 3750 int4 per slice

// flags bits: bit0 = batch col (score2 target), bit1 = needed row for gather1/MLP1

// ---- claim batch nodes; dense-remap them to bidx in [0, nb) ----
__global__ void k_flag(const int* __restrict__ users, const int* __restrict__ items,
                       int* flags, int* __restrict__ bidx, int* __restrict__ nb) {
    const int t = blockIdx.x * blockDim.x + threadIdx.x;
    if (t >= 2 * B) return;
    const int node = (t < B) ? users[t] : items[t - B] + NU;
    const int old = atomicOr(&flags[node], 1);
    if (!(old & 1)) bidx[node] = atomicAdd(nb, 1);   // unique claimer assigns index
}

// ---- degree histogram, zero global atomics: per-(chunk,slice) byte-packed LDS
//      histogram, flushed to a private copy. Safe: max degree ~35 << 255. ----
__global__ void __launch_bounds__(256) k_hist(const int* __restrict__ row,
                                              unsigned int* __restrict__ hcopy) {
    __shared__ unsigned int lh[CWORDS];
    const int ci = blockIdx.x / NSLICE;
    const int si = blockIdx.x % NSLICE;
    const int lo = ci * CHUNK;
    const int cw = (ci == NCHUNK - 1) ? (WORDS - (NCHUNK - 1) * CWORDS) : CWORDS;
    for (int w = threadIdx.x; w < cw; w += 256) lh[w] = 0;
    __syncthreads();
    const int4* r4 = reinterpret_cast<const int4*>(row) + (size_t)si * SLICE4;
    const unsigned int span = (unsigned)(cw * 4);
    for (int t = threadIdx.x; t < SLICE4; t += 256) {
        const int4 r = r4[t];
        int v;
        v = r.x - lo; if ((unsigned)v < span) atomicAdd(&lh[v >> 2], 1u << (8 * (v & 3)));
        v = r.y - lo; if ((unsigned)v < span) atomicAdd(&lh[v >> 2], 1u << (8 * (v & 3)));
        v = r.z - lo; if ((unsigned)v < span) atomicAdd(&lh[v >> 2], 1u << (8 * (v & 3)));
        v = r.w - lo; if ((unsigned)v < span) atomicAdd(&lh[v >> 2], 1u << (8 * (v & 3)));
    }
    __syncthreads();
    unsigned int* dst = hcopy + (size_t)si * WORDS + ci * CWORDS;
    for (int w = threadIdx.x; w < cw; w += 256) dst[w] = lh[w];
}

// ---- full edge pass: batch-col fixed-slot CSR fill + mark source rows (bit1) ----
__global__ void k_mark(const int* __restrict__ row, const int* __restrict__ col,
                       const int* __restrict__ bidx,
                       int* __restrict__ cntBd, int* __restrict__ csrBd, int* flags) {
    const int t = blockIdx.x * blockDim.x + threadIdx.x;
    if (t >= NE4) return;
    const int4 r = reinterpret_cast<const int4*>(row)[t];
    const int4 c = reinterpret_cast<const int4*>(col)[t];
    // flags[rr] |= 2 races only with other |=2 (bit0 frozen since k_flag) -> benign
    #define E1(rr, cc) if (flags[cc] & 1) { \
        const int bi = bidx[cc]; \
        const int s = atomicAdd(&cntBd[bi], 1); \
        csrBd[bi * CAPB + s] = rr; \
        flags[rr] |= 2; }
    E1(r.x, c.x) E1(r.y, c.y) E1(r.z, c.z) E1(r.w, c.w)
    #undef E1
}

// ---- reduce 80 histogram copies -> deg -> dinv, fused with bit1-list compaction ----
__global__ void k_dinvc(const unsigned int* __restrict__ hcopy,
                        float* __restrict__ dinv, const int* __restrict__ flags,
                        int* __restrict__ list, int* __restrict__ ncnt) {
    const int w = blockIdx.x * blockDim.x + threadIdx.x;
    if (w >= RWORDS) return;
    unsigned int s = 0;
    #pragma unroll 8
    for (int si = 0; si < NSLICE; ++si) s += hcopy[(size_t)si * WORDS + w];
    const int d0 = s & 255, d1 = (s >> 8) & 255, d2 = (s >> 16) & 255, d3 = (int)(s >> 24);
    float4 dv;
    dv.x = d0 > 0 ? 1.0f / sqrtf((float)d0) : 0.0f;
    dv.y = d1 > 0 ? 1.0f / sqrtf((float)d1) : 0.0f;
    dv.z = d2 > 0 ? 1.0f / sqrtf((float)d2) : 0.0f;
    dv.w = d3 > 0 ? 1.0f / sqrtf((float)d3) : 0.0f;
    reinterpret_cast<float4*>(dinv)[w] = dv;
    const int4 fl = reinterpret_cast<const int4*>(flags)[w];
    const int n0 = w * 4;
    if (fl.x & 2) list[atomicAdd(ncnt, 1)] = n0;       // wave-aggregated by compiler
    if (fl.y & 2) list[atomicAdd(ncnt, 1)] = n0 + 1;
    if (fl.z & 2) list[atomicAdd(ncnt, 1)] = n0 + 2;
    if (fl.w & 2) list[atomicAdd(ncnt, 1)] = n0 + 3;
}

// ---- pass 2: fill fixed-slot gather CSR for marked cols (single pass, no scan) ----
__global__ void k_pass2(const int* __restrict__ row, const int* __restrict__ col,
                        const int* __restrict__ flags,
                        int* __restrict__ cnt2d, int* __restrict__ csr2d) {
    const int t = blockIdx.x * blockDim.x + threadIdx.x;
    if (t >= NE4) return;
    const int4 r = reinterpret_cast<const int4*>(row)[t];
    const int4 c = reinterpret_cast<const int4*>(col)[t];
    #define E2(rr, cc) if (flags[cc] & 2) { \
        const int s = atomicAdd(&cnt2d[cc], 1); \
        csr2d[cc * CAP2 + s] = rr; }
    E2(r.x, c.x) E2(r.y, c.y) E2(r.z, c.z) E2(r.w, c.w)
    #undef E2
}

// ---- propagate 1, lazily: one wave per listed node; 4-deep gather ILP ----
// (fusion with MLP1 tried in R11: regressed — serial MLP chain inside the
//  gather loop stalls the memory pipeline; keep kernels split.)
__global__ void k_gather1(const int* __restrict__ list, const int* __restrict__ ncnt,
                          const int* __restrict__ cnt2d, const int* __restrict__ csr2d,
                          const float* __restrict__ dinv,
                          const float* __restrict__ embU, const float* __restrict__ embI,
                          float* __restrict__ out) {
    const int lane = threadIdx.x & 63;
    const int idx = blockIdx.x * (blockDim.x >> 6) + (threadIdx.x >> 6);
    if (idx >= *ncnt) return;
    const int c = list[idx];
    const int ne = cnt2d[c];
    const int* es = csr2d + (size_t)c * CAP2;
    float a0 = 0.0f, a1 = 0.0f, a2 = 0.0f, a3 = 0.0f;
    int e = 0;
    for (; e + 3 < ne; e += 4) {       // 4-deep ILP: int4 ids + 8 loads in flight
        const int4 r = *reinterpret_cast<const int4*>(es + e);   // 16B-aligned
        const float d0 = dinv[r.x], d1 = dinv[r.y], d2 = dinv[r.z], d3 = dinv[r.w];
        const float* s0 = (r.x < NU) ? embU + (size_t)r.x * D : embI + (size_t)(r.x - NU) * D;
        const float* s1 = (r.y < NU) ? embU + (size_t)r.y * D : embI + (size_t)(r.y - NU) * D;
        const float* s2 = (r.z < NU) ? embU + (size_t)r.z * D : embI + (size_t)(r.z - NU) * D;
        const float* s3 = (r.w < NU) ? embU + (size_t)r.w * D : embI + (size_t)(r.w - NU) * D;
        a0 = fmaf(d0, s0[lane], a0);
        a1 = fmaf(d1, s1[lane], a1);
        a2 = fmaf(d2, s2[lane], a2);
        a3 = fmaf(d3, s3[lane], a3);
    }
    for (; e < ne; ++e) {
        const int r = es[e];
        const float* s = (r < NU) ? embU + (size_t)r * D : embI + (size_t)(r - NU) * D;
        a0 = fmaf(dinv[r], s[lane], a0);
    }
    out[(size_t)c * D + lane] = dinv[c] * ((a0 + a1) + (a2 + a3));
}

// ---- lazy in-place relu(x @ W.T + b) on listed rows only, LDS-free ----
__global__ void __launch_bounds__(256) k_mlp_relu(const int* __restrict__ list,
                                                  const int* __restrict__ ncnt,
                                                  float* __restrict__ emb,
                                                  const float* __restrict__ W,
                                                  const float* __restrict__ b) {
    const int lane = threadIdx.x & 63;
    float w[D];
    #pragma unroll
    for (int k4 = 0; k4 < D / 4; ++k4) {
        const float4 v = *reinterpret_cast<const float4*>(W + (size_t)lane * D + k4 * 4);
        w[k4 * 4 + 0] = v.x; w[k4 * 4 + 1] = v.y;
        w[k4 * 4 + 2] = v.z; w[k4 * 4 + 3] = v.w;
    }
    const float bias = b[lane];

    const int n = *ncnt;
    const int wid = blockIdx.x * (blockDim.x >> 6) + (threadIdx.x >> 6);
    const int nw  = gridDim.x * (blockDim.x >> 6);
    for (int i4 = wid * 4; i4 < n; i4 += nw * 4) {
        const int r0 = list[i4];
        const int r1 = (i4 + 1 < n) ? list[i4 + 1] : r0;   // tail: duplicate row0
        const int r2 = (i4 + 2 < n) ? list[i4 + 2] : r0;   // (same input -> same
        const int r3 = (i4 + 3 < n) ? list[i4 + 3] : r0;   //  result, write benign)
        float* x0 = emb + (size_t)r0 * D;
        float* x1 = emb + (size_t)r1 * D;
        float* x2 = emb + (size_t)r2 * D;
        float* x3 = emb + (size_t)r3 * D;
        const float xv0 = x0[lane], xv1 = x1[lane], xv2 = x2[lane], xv3 = x3[lane];
        float a0 = bias, a1 = bias, a2 = bias, a3 = bias;
        #pragma unroll
        for (int k = 0; k < D; ++k) {
            const float wk = w[k];
            a0 = fmaf(__int_as_float(__builtin_amdgcn_readlane(__float_as_int(xv0), k)), wk, a0);
            a1 = fmaf(__int_as_float(__builtin_amdgcn_readlane(__float_as_int(xv1), k)), wk, a1);
            a2 = fmaf(__int_as_float(__builtin_amdgcn_readlane(__float_as_int(xv2), k)), wk, a2);
            a3 = fmaf(__int_as_float(__builtin_amdgcn_readlane(__float_as_int(xv3), k)), wk, a3);
        }
        x0[lane] = fmaxf(a0, 0.0f);
        x1[lane] = fmaxf(a1, 0.0f);
        x2[lane] = fmaxf(a2, 0.0f);
        x3[lane] = fmaxf(a3, 0.0f);
    }
}

// ---- fused propagate2(batch fixed-slot CSR) + MLP2 + dot, per batch pair ----
__global__ void k_score2(const int* __restrict__ users, const int* __restrict__ items,
                         const int* __restrict__ bidx, const int* __restrict__ cntBd,
                         const int* __restrict__ csrBd,
                         const float* __restrict__ dinv, const float* __restrict__ embA,
                         const float* __restrict__ W, const float* __restrict__ b,
                         float* __restrict__ out) {
    __shared__ float sWt[D * D];   // sWt[k*D + j] = W[j*D + k]
    __shared__ float sb[D];
    __shared__ float sx[4][D];
    for (int i = threadIdx.x; i < D * D; i += blockDim.x)
        sWt[i] = W[(size_t)(i & 63) * D + (i >> 6)];
    if (threadIdx.x < D) sb[threadIdx.x] = b[threadIdx.x];
    __syncthreads();
    const int lane = threadIdx.x & 63;
    const int wid  = threadIdx.x >> 6;
    const int p = blockIdx.x * (blockDim.x >> 6) + wid;
    if (p >= B) return;

    float y[2];
    const int node[2] = { users[p], items[p] + NU };
    #pragma unroll
    for (int t = 0; t < 2; ++t) {
        const int c = node[t];
        const int bi = bidx[c];
        const int n = cntBd[bi];
        const int* es = csrBd + (size_t)bi * CAPB;
        float acc = 0.0f;
        for (int e = 0; e < n; ++e) {
            const int r = es[e];
            acc = fmaf(dinv[r], embA[(size_t)r * D + lane], acc);
        }
        sx[wid][lane] = dinv[c] * acc;
        float yv = sb[lane];
        #pragma unroll
        for (int k = 0; k < D; ++k)
            yv = fmaf(sx[wid][k], sWt[k * D + lane], yv);
        y[t] = yv;
    }
    float prod = y[0] * y[1];
    #pragma unroll
    for (int off = 32; off >= 1; off >>= 1) prod += __shfl_down(prod, off, 64);
    if (lane == 0) out[p] = prod;
}

extern "C" void kernel_launch(void* const* d_in, const int* in_sizes, int n_in,
                              void* d_out, int out_size, void* d_ws, size_t ws_size,
                              hipStream_t stream) {
    const int*   users    = (const int*)d_in[0];
    const int*   items    = (const int*)d_in[1];
    const int*   edge     = (const int*)d_in[2];   // [2][NE]
    const float* user_emb = (const float*)d_in[3];
    const float* item_emb = (const float*)d_in[4];
    const float* W1       = (const float*)d_in[5];
    const float* b1       = (const float*)d_in[6];
    const float* W2       = (const float*)d_in[7];
    const float* b2       = (const float*)d_in[8];
    float*       out      = (float*)d_out;

    const int* row  = edge;
    const int* colp = edge + NE;

    // workspace layout (int offsets; zeroed region contiguous at the front):
    int*   flags = (int*)d_ws;                  // @0        150016  [zeroed]
    int*   cnt2d = (int*)d_ws + 150016;         //           150016  [zeroed]
    int*   cntBd = (int*)d_ws + 300032;         //           8448    [zeroed]
    int*   nb    = (int*)d_ws + 308480;         //           16      [zeroed]
    int*   ncnt  = (int*)d_ws + 308496;         //           16     (zero ends 308512)
    float* dinv  = (float*)d_ws + 308512;       //           150016
    int*   bidx  = (int*)d_ws + 458528;         //           150016
    int*   list  = (int*)d_ws + 608544;         //           150016
    int*   csrBd = (int*)d_ws + 758560;         //           540672 (8448*64)
    int*   csr2d = (int*)d_ws + 1299232;        //           6000640 (150016*40)
    float* embA  = (float*)d_ws + 7299872;      //           9600000
    // hcopy (80*37504 = 3000320 ints) aliases csr2d: dead until k_pass2 runs,
    // and k_dinvc (its last reader) precedes k_pass2.
    unsigned int* hcopy = (unsigned int*)csr2d;

    hipMemsetAsync(flags, 0, (size_t)308512 * sizeof(int), stream);

    k_flag <<<(2 * B + 255) / 256, 256, 0, stream>>>(users, items, flags, bidx, nb);
    // degree histogram via LDS byte counters (no global atomics)
    k_hist <<<NCHUNK * NSLICE, 256, 0, stream>>>(row, hcopy);
    // batch CSR fill + source marking, one full edge pass
    k_mark <<<(NE4 + 255) / 256, 256, 0, stream>>>(row, colp, bidx, cntBd, csrBd, flags);
    // reduce histogram copies -> dinv ; compact bit1 list
    k_dinvc<<<(RWORDS + 255) / 256, 256, 0, stream>>>(hcopy, dinv, flags, list, ncnt);
    // gather CSR fill (marked cols only), one full edge pass, no scans
    k_pass2<<<(NE4 + 255) / 256, 256, 0, stream>>>(row, colp, flags, cnt2d, csr2d);

    // lazy propagate-1 (one wave per listed node, 4-deep ILP) + MLP1
    k_gather1 <<<(NN + 3) / 4, 256, 0, stream>>>(list, ncnt, cnt2d, csr2d, dinv,
                                                 user_emb, item_emb, embA);
    k_mlp_relu<<<2048, 256, 0, stream>>>(list, ncnt, embA, W1, b1);
    // fused propagate-2 + MLP2 + dot at the 4096 batch pairs
    k_score2<<<B / 4, 256, 0, stream>>>(users, items, bidx, cntBd, csrBd, dinv, embA,
                                        W2, b2, out);
}

// Round 13
// 172.873 us; speedup vs baseline: 1.1229x; 1.0307x over previous
//
#include <hip/hip_runtime.h>
#include <math.h>

constexpr int NU = 100000;
constexpr int NI = 50000;
constexpr int NN = 150000;   // NU + NI
constexpr int D  = 64;
constexpr int NE = 1200000;
constexpr int NE4 = NE / 4;
constexpr int B  = 4096;
constexpr int CAPB = 64;     // max in-degree of a batch col   (Poisson(8): max ~35)
constexpr int CAP2 = 40;     // max in-degree of a marked col  (P(>=40) ~ 1e-10)

// LDS degree histogram geometry
constexpr int NCHUNK = 3;
constexpr int CHUNK  = 65536;        // nodes per chunk (byte counters -> 64 KB LDS)
constexpr int CWORDS = CHUNK / 4;    // 16384 words
constexpr int WORDS  = 37504;        // padded word stride per slice copy (NN/4 = 37500)
constexpr int RWORDS = 37500;        // real words
constexpr int NSLICE = 80;
constexpr int SLICE4 = NE4 / NSLICE; // 3750 int4 per slice

constexpr int ZINTS = 308512;        // zeroed workspace prefix (ints)
constexpr int ZN4   = ZINTS / 4;     // 77128 int4

// flags bits: bit0 = batch col (score2 target), bit1 = needed row for gather1/MLP1

// ---- custom zero: rocclr fillBuffer measured at 41 us for 1.2 MB (R12); this
//      one-shot int4 store grid does it in ~3 us ----
__global__ void k_zero(int4* __restrict__ p) {
    const int i = blockIdx.x * blockDim.x + threadIdx.x;
    if (i < ZN4) p[i] = make_int4(0, 0, 0, 0);
}

// ---- claim batch nodes; dense-remap them to bidx in [0, nb) ----
__global__ void k_flag(const int* __restrict__ users, const int* __restrict__ items,
                       int* flags, int* __restrict__ bidx, int* __restrict__ nb) {
    const int t = blockIdx.x * blockDim.x + threadIdx.x;
    if (t >= 2 * B) return;
    const int node = (t < B) ? users[t] : items[t - B] + NU;
    const int old = atomicOr(&flags[node], 1);
    if (!(old & 1)) bidx[node] = atomicAdd(nb, 1);   // unique claimer assigns index
}

// ---- degree histogram, zero global atomics: per-(chunk,slice) byte-packed LDS
//      histogram, flushed to a private copy. Safe: max degree ~35 << 255. ----
__global__ void __launch_bounds__(256) k_hist(const int* __restrict__ row,
                                              unsigned int* __restrict__ hcopy) {
    __shared__ unsigned int lh[CWORDS];
    const int ci = blockIdx.x / NSLICE;
    const int si = blockIdx.x % NSLICE;
    const int lo = ci * CHUNK;
    const int cw = (ci == NCHUNK - 1) ? (WORDS - (NCHUNK - 1) * CWORDS) : CWORDS;
    for (int w = threadIdx.x; w < cw; w += 256) lh[w] = 0;
    __syncthreads();
    const int4* r4 = reinterpret_cast<const int4*>(row) + (size_t)si * SLICE4;
    const unsigned int span = (unsigned)(cw * 4);
    for (int t = threadIdx.x; t < SLICE4; t += 256) {
        const int4 r = r4[t];
        int v;
        v = r.x - lo; if ((unsigned)v < span) atomicAdd(&lh[v >> 2], 1u << (8 * (v & 3)));
        v = r.y - lo; if ((unsigned)v < span) atomicAdd(&lh[v >> 2], 1u << (8 * (v & 3)));
        v = r.z - lo; if ((unsigned)v < span) atomicAdd(&lh[v >> 2], 1u << (8 * (v & 3)));
        v = r.w - lo; if ((unsigned)v < span) atomicAdd(&lh[v >> 2], 1u << (8 * (v & 3)));
    }
    __syncthreads();
    unsigned int* dst = hcopy + (size_t)si * WORDS + ci * CWORDS;
    for (int w = threadIdx.x; w < cw; w += 256) dst[w] = lh[w];
}

// ---- full edge pass: batch-col fixed-slot CSR fill + mark source rows (bit1) ----
__global__ void k_mark(const int* __restrict__ row, const int* __restrict__ col,
                       const int* __restrict__ bidx,
                       int* __restrict__ cntBd, int* __restrict__ csrBd, int* flags) {
    const int t = blockIdx.x * blockDim.x + threadIdx.x;
    if (t >= NE4) return;
    const int4 r = reinterpret_cast<const int4*>(row)[t];
    const int4 c = reinterpret_cast<const int4*>(col)[t];
    // flags[rr] |= 2 races only with other |=2 (bit0 frozen since k_flag) -> benign
    #define E1(rr, cc) if (flags[cc] & 1) { \
        const int bi = bidx[cc]; \
        const int s = atomicAdd(&cntBd[bi], 1); \
        csrBd[bi * CAPB + s] = rr; \
        flags[rr] |= 2; }
    E1(r.x, c.x) E1(r.y, c.y) E1(r.z, c.z) E1(r.w, c.w)
    #undef E1
}

// ---- reduce 80 histogram copies -> deg -> dinv, fused with bit1-list compaction ----
__global__ void k_dinvc(const unsigned int* __restrict__ hcopy,
                        float* __restrict__ dinv, const int* __restrict__ flags,
                        int* __restrict__ list, int* __restrict__ ncnt) {
    const int w = blockIdx.x * blockDim.x + threadIdx.x;
    if (w >= RWORDS) return;
    unsigned int s = 0;
    #pragma unroll 8
    for (int si = 0; si < NSLICE; ++si) s += hcopy[(size_t)si * WORDS + w];
    const int d0 = s & 255, d1 = (s >> 8) & 255, d2 = (s >> 16) & 255, d3 = (int)(s >> 24);
    float4 dv;
    dv.x = d0 > 0 ? 1.0f / sqrtf((float)d0) : 0.0f;
    dv.y = d1 > 0 ? 1.0f / sqrtf((float)d1) : 0.0f;
    dv.z = d2 > 0 ? 1.0f / sqrtf((float)d2) : 0.0f;
    dv.w = d3 > 0 ? 1.0f / sqrtf((float)d3) : 0.0f;
    reinterpret_cast<float4*>(dinv)[w] = dv;
    const int4 fl = reinterpret_cast<const int4*>(flags)[w];
    const int n0 = w * 4;
    if (fl.x & 2) list[atomicAdd(ncnt, 1)] = n0;       // wave-aggregated by compiler
    if (fl.y & 2) list[atomicAdd(ncnt, 1)] = n0 + 1;
    if (fl.z & 2) list[atomicAdd(ncnt, 1)] = n0 + 2;
    if (fl.w & 2) list[atomicAdd(ncnt, 1)] = n0 + 3;
}

// ---- pass 2: fill fixed-slot gather CSR for marked cols (single pass, no scan) ----
__global__ void k_pass2(const int* __restrict__ row, const int* __restrict__ col,
                        const int* __restrict__ flags,
                        int* __restrict__ cnt2d, int* __restrict__ csr2d) {
    const int t = blockIdx.x * blockDim.x + threadIdx.x;
    if (t >= NE4) return;
    const int4 r = reinterpret_cast<const int4*>(row)[t];
    const int4 c = reinterpret_cast<const int4*>(col)[t];
    #define E2(rr, cc) if (flags[cc] & 2) { \
        const int s = atomicAdd(&cnt2d[cc], 1); \
        csr2d[cc * CAP2 + s] = rr; }
    E2(r.x, c.x) E2(r.y, c.y) E2(r.z, c.z) E2(r.w, c.w)
    #undef E2
}

// ---- propagate 1, lazily: one wave per listed node; 4-deep gather ILP ----
// (fusion with MLP1 tried in R11: regressed — serial MLP chain inside the
//  gather loop stalls the memory pipeline; keep kernels split.)
__global__ void k_gather1(const int* __restrict__ list, const int* __restrict__ ncnt,
                          const int* __restrict__ cnt2d, const int* __restrict__ csr2d,
                          const float* __restrict__ dinv,
                          const float* __restrict__ embU, const float* __restrict__ embI,
                          float* __restrict__ out) {
    const int lane = threadIdx.x & 63;
    const int idx = blockIdx.x * (blockDim.x >> 6) + (threadIdx.x >> 6);
    if (idx >= *ncnt) return;
    const int c = list[idx];
    const int ne = cnt2d[c];
    const int* es = csr2d + (size_t)c * CAP2;
    float a0 = 0.0f, a1 = 0.0f, a2 = 0.0f, a3 = 0.0f;
    int e = 0;
    for (; e + 3 < ne; e += 4) {       // 4-deep ILP: int4 ids + 8 loads in flight
        const int4 r = *reinterpret_cast<const int4*>(es + e);   // 16B-aligned
        const float d0 = dinv[r.x], d1 = dinv[r.y], d2 = dinv[r.z], d3 = dinv[r.w];
        const float* s0 = (r.x < NU) ? embU + (size_t)r.x * D : embI + (size_t)(r.x - NU) * D;
        const float* s1 = (r.y < NU) ? embU + (size_t)r.y * D : embI + (size_t)(r.y - NU) * D;
        const float* s2 = (r.z < NU) ? embU + (size_t)r.z * D : embI + (size_t)(r.z - NU) * D;
        const float* s3 = (r.w < NU) ? embU + (size_t)r.w * D : embI + (size_t)(r.w - NU) * D;
        a0 = fmaf(d0, s0[lane], a0);
        a1 = fmaf(d1, s1[lane], a1);
        a2 = fmaf(d2, s2[lane], a2);
        a3 = fmaf(d3, s3[lane], a3);
    }
    for (; e < ne; ++e) {
        const int r = es[e];
        const float* s = (r < NU) ? embU + (size_t)r * D : embI + (size_t)(r - NU) * D;
        a0 = fmaf(dinv[r], s[lane], a0);
    }
    out[(size_t)c * D + lane] = dinv[c] * ((a0 + a1) + (a2 + a3));
}

// ---- lazy in-place relu(x @ W.T + b) on listed rows only, LDS-free ----
__global__ void __launch_bounds__(256) k_mlp_relu(const int* __restrict__ list,
                                                  const int* __restrict__ ncnt,
                                                  float* __restrict__ emb,
                                                  const float* __restrict__ W,
                                                  const float* __restrict__ b) {
    const int lane = threadIdx.x & 63;
    float w[D];
    #pragma unroll
    for (int k4 = 0; k4 < D / 4; ++k4) {
        const float4 v = *reinterpret_cast<const float4*>(W + (size_t)lane * D + k4 * 4);
        w[k4 * 4 + 0] = v.x; w[k4 * 4 + 1] = v.y;
        w[k4 * 4 + 2] = v.z; w[k4 * 4 + 3] = v.w;
    }
    const float bias = b[lane];

    const int n = *ncnt;
    const int wid = blockIdx.x * (blockDim.x >> 6) + (threadIdx.x >> 6);
    const int nw  = gridDim.x * (blockDim.x >> 6);
    for (int i4 = wid * 4; i4 < n; i4 += nw * 4) {
        const int r0 = list[i4];
        const int r1 = (i4 + 1 < n) ? list[i4 + 1] : r0;   // tail: duplicate row0
        const int r2 = (i4 + 2 < n) ? list[i4 + 2] : r0;   // (same input -> same
        const int r3 = (i4 + 3 < n) ? list[i4 + 3] : r0;   //  result, write benign)
        float* x0 = emb + (size_t)r0 * D;
        float* x1 = emb + (size_t)r1 * D;
        float* x2 = emb + (size_t)r2 * D;
        float* x3 = emb + (size_t)r3 * D;
        const float xv0 = x0[lane], xv1 = x1[lane], xv2 = x2[lane], xv3 = x3[lane];
        float a0 = bias, a1 = bias, a2 = bias, a3 = bias;
        #pragma unroll
        for (int k = 0; k < D; ++k) {
            const float wk = w[k];
            a0 = fmaf(__int_as_float(__builtin_amdgcn_readlane(__float_as_int(xv0), k)), wk, a0);
            a1 = fmaf(__int_as_float(__builtin_amdgcn_readlane(__float_as_int(xv1), k)), wk, a1);
            a2 = fmaf(__int_as_float(__builtin_amdgcn_readlane(__float_as_int(xv2), k)), wk, a2);
            a3 = fmaf(__int_as_float(__builtin_amdgcn_readlane(__float_as_int(xv3), k)), wk, a3);
        }
        x0[lane] = fmaxf(a0, 0.0f);
        x1[lane] = fmaxf(a1, 0.0f);
        x2[lane] = fmaxf(a2, 0.0f);
        x3[lane] = fmaxf(a3, 0.0f);
    }
}

// ---- fused propagate2 + MLP2 + dot: one wave per (pair, node) — 2x TLP vs
//      pair-per-wave (R12: 40 us, occ 26%, VALUBusy 6% = latency-bound).
//      4-deep gather ILP; register-held W2 row + readlane MLP (no 16KB LDS). ----
__global__ void __launch_bounds__(256) k_score2(const int* __restrict__ users,
                                                const int* __restrict__ items,
                                                const int* __restrict__ bidx,
                                                const int* __restrict__ cntBd,
                                                const int* __restrict__ csrBd,
                                                const float* __restrict__ dinv,
                                                const float* __restrict__ embA,
                                                const float* __restrict__ W,
                                                const float* __restrict__ b,
                                                float* __restrict__ out) {
    __shared__ float sy[2][2][D];        // [pair-in-block][t][lane]
    const int lane = threadIdx.x & 63;
    const int wid  = threadIdx.x >> 6;   // 0..3
    const int pp   = wid >> 1;           // pair slot in block
    const int t    = wid & 1;            // 0 = user node, 1 = item node
    const int p    = blockIdx.x * 2 + pp;    // grid = B/2 -> p < B always

    float w[D];                          // W2 row `lane` (L1-hot across waves)
    #pragma unroll
    for (int k4 = 0; k4 < D / 4; ++k4) {
        const float4 v = *reinterpret_cast<const float4*>(W + (size_t)lane * D + k4 * 4);
        w[k4 * 4 + 0] = v.x; w[k4 * 4 + 1] = v.y;
        w[k4 * 4 + 2] = v.z; w[k4 * 4 + 3] = v.w;
    }

    const int c  = (t == 0) ? users[p] : items[p] + NU;
    const int bi = bidx[c];
    const int n  = cntBd[bi];
    const int* es = csrBd + (size_t)bi * CAPB;
    float a0 = 0.0f, a1 = 0.0f, a2 = 0.0f, a3 = 0.0f;
    int e = 0;
    for (; e + 3 < n; e += 4) {          // 4-deep ILP (csrBd rows 256B-aligned)
        const int4 r = *reinterpret_cast<const int4*>(es + e);
        a0 = fmaf(dinv[r.x], embA[(size_t)r.x * D + lane], a0);
        a1 = fmaf(dinv[r.y], embA[(size_t)r.y * D + lane], a1);
        a2 = fmaf(dinv[r.z], embA[(size_t)r.z * D + lane], a2);
        a3 = fmaf(dinv[r.w], embA[(size_t)r.w * D + lane], a3);
    }
    for (; e < n; ++e) {
        const int r = es[e];
        a0 = fmaf(dinv[r], embA[(size_t)r * D + lane], a0);
    }
    const float x = dinv[c] * ((a0 + a1) + (a2 + a3));   // prop-2 value at lane

    float y = b[lane];
    #pragma unroll
    for (int k = 0; k < D; ++k)
        y = fmaf(__int_as_float(__builtin_amdgcn_readlane(__float_as_int(x), k)),
                 w[k], y);
    sy[pp][t][lane] = y;
    __syncthreads();
    if (t == 0) {
        float prod = sy[pp][0][lane] * sy[pp][1][lane];
        #pragma unroll
        for (int off = 32; off >= 1; off >>= 1) prod += __shfl_down(prod, off, 64);
        if (lane == 0) out[p] = prod;
    }
}

extern "C" void kernel_launch(void* const* d_in, const int* in_sizes, int n_in,
                              void* d_out, int out_size, void* d_ws, size_t ws_size,
                              hipStream_t stream) {
    const int*   users    = (const int*)d_in[0];
    const int*   items    = (const int*)d_in[1];
    const int*   edge     = (const int*)d_in[2];   // [2][NE]
    const float* user_emb = (const float*)d_in[3];
    const float* item_emb = (const float*)d_in[4];
    const float* W1       = (const float*)d_in[5];
    const float* b1       = (const float*)d_in[6];
    const float* W2       = (const float*)d_in[7];
    const float* b2       = (const float*)d_in[8];
    float*       out      = (float*)d_out;

    const int* row  = edge;
    const int* colp = edge + NE;

    // workspace layout (int offsets; zeroed region contiguous at the front):
    int*   flags = (int*)d_ws;                  // @0        150016  [zeroed]
    int*   cnt2d = (int*)d_ws + 150016;         //           150016  [zeroed]
    int*   cntBd = (int*)d_ws + 300032;         //           8448    [zeroed]
    int*   nb    = (int*)d_ws + 308480;         //           16      [zeroed]
    int*   ncnt  = (int*)d_ws + 308496;         //           16     (zero ends 308512)
    float* dinv  = (float*)d_ws + 308512;       //           150016
    int*   bidx  = (int*)d_ws + 458528;         //           150016
    int*   list  = (int*)d_ws + 608544;         //           150016
    int*   csrBd = (int*)d_ws + 758560;         //           540672 (8448*64)
    int*   csr2d = (int*)d_ws + 1299232;        //           6000640 (150016*40)
    float* embA  = (float*)d_ws + 7299872;      //           9600000
    // hcopy (80*37504 = 3000320 ints) aliases csr2d: dead until k_pass2 runs,
    // and k_dinvc (its last reader) precedes k_pass2.
    unsigned int* hcopy = (unsigned int*)csr2d;

    k_zero <<<(ZN4 + 255) / 256, 256, 0, stream>>>((int4*)d_ws);

    k_flag <<<(2 * B + 255) / 256, 256, 0, stream>>>(users, items, flags, bidx, nb);
    // degree histogram via LDS byte counters (no global atomics)
    k_hist <<<NCHUNK * NSLICE, 256, 0, stream>>>(row, hcopy);
    // batch CSR fill + source marking, one full edge pass
    k_mark <<<(NE4 + 255) / 256, 256, 0, stream>>>(row, colp, bidx, cntBd, csrBd, flags);
    // reduce histogram copies -> dinv ; compact bit1 list
    k_dinvc<<<(RWORDS + 255) / 256, 256, 0, stream>>>(hcopy, dinv, flags, list, ncnt);
    // gather CSR fill (marked cols only), one full edge pass, no scans
    k_pass2<<<(NE4 + 255) / 256, 256, 0, stream>>>(row, colp, flags, cnt2d, csr2d);

    // lazy propagate-1 (one wave per listed node, 4-deep ILP) + MLP1
    k_gather1 <<<(NN + 3) / 4, 256, 0, stream>>>(list, ncnt, cnt2d, csr2d, dinv,
                                                 user_emb, item_emb, embA);
    k_mlp_relu<<<2048, 256, 0, stream>>>(list, ncnt, embA, W1, b1);
    // fused propagate-2 + MLP2 + dot: one wave per (pair, node)
    k_score2<<<B / 2, 256, 0, stream>>>(users, items, bidx, cntBd, csrBd, dinv, embA,
                                        W2, b2, out);
}